// Round 2
// baseline (185.337 us; speedup 1.0000x reference)
//
#include <hip/hip_runtime.h>

// Binary-weight dense: out[M,N] = scale * x[M,K] @ W[K,N], W = kernel ? +1 : -1
// M = 16384, K = 1024, N = 1024.
// R7: R6's fused GEMM (convert_x folded into A-staging) with the mode-detect
// bug fixed. R6 guessed the bool encoding from in_sizes[1]; in_sizes is in
// ELEMENTS (see harness: out_buf.to_numpy(np.float32, (out_size,))), so the
// guess selected byte mode while the harness uploads int32 bools -> garbage W
// (absmax 7.78 = uncorrelated-output signature). Fix: always run the R5-proven
// device-side detect_mode (1 block, ~2 us) and let convert_w read the flag.
// Fused GEMM unchanged from R6: A reg-staged (global fp32 -> v_cvt_pk_bf16_f32
// -> ds_write_b128 with XOR-chunk LDS scatter, linear global reads); B staged
// via global_load_lds w=16 with source-side swizzle; 128x128x64 tile,
// 16x16x32 bf16 MFMA, XCD-aware block swizzle.

#define M_TOT 16384
#define N_TOT 1024
#define K_TOT 1024

typedef __attribute__((ext_vector_type(8))) short bf16x8;
typedef __attribute__((ext_vector_type(4))) float f32x4;

__device__ __forceinline__ unsigned short f2bf(float f) {
    unsigned int u = __builtin_bit_cast(unsigned int, f);
    u += 0x7FFFu + ((u >> 16) & 1u);   // round-to-nearest-even
    return (unsigned short)(u >> 16);
}

// v_cvt_pk_bf16_f32: 2 fp32 -> packed 2x bf16 (lo = S0, hi = S1), RNE.
// No builtin on gfx950 -> inline asm (learn_hip m240; layout verified by
// m214v22's refcheck'd usage packing adjacent pairs in order).
__device__ __forceinline__ unsigned int cvt_pk_bf16(float lo, float hi) {
    unsigned int r;
    asm("v_cvt_pk_bf16_f32 %0, %1, %2" : "=v"(r) : "v"(lo), "v"(hi));
    return r;
}

// int32 bools -> all words are 0/1; byte-packed bools -> some word among the
// first 1024 exceeds 1 with overwhelming probability (P(miss) ~ (1/8)^1024).
__global__ void detect_mode(const unsigned int* __restrict__ k32, int* __restrict__ flag) {
    __shared__ int s;
    if (threadIdx.x == 0) s = 0;
    __syncthreads();
    int bad = 0;
    for (int i = threadIdx.x; i < 1024; i += 256)
        if (k32[i] > 1u) bad = 1;
    if (bad) atomicOr(&s, 1);
    __syncthreads();
    if (threadIdx.x == 0) flag[0] = s;   // 1 = byte mode, 0 = int32 mode
}

// ---------------- prepass: W bools [k][n] -> +-1 bf16 [n][k] ----------------
__global__ __launch_bounds__(256) void convert_w(
    const void* __restrict__ w_raw, unsigned short* __restrict__ wt,
    const int* __restrict__ mode_p)
{
    __shared__ unsigned short tile[64 * 72];
    const int tid = threadIdx.x;
    const int k0 = (blockIdx.x & 15) * 64;
    const int n0 = (blockIdx.x >> 4) * 64;
    const int row = tid >> 2;            // k-local
    const int seg = (tid & 3) * 16;      // n-local group of 16

    if (mode_p[0] == 0) {
        // int32 mode: 16 ints = 4 uint4 per thread
        const unsigned int* w = (const unsigned int*)w_raw;
        const uint4* src = reinterpret_cast<const uint4*>(
            w + (size_t)(k0 + row) * N_TOT + n0 + seg);
        #pragma unroll
        for (int q = 0; q < 4; ++q) {
            uint4 v = src[q];
            ushort4 h;
            h.x = v.x ? 0x3F80u : 0xBF80u;
            h.y = v.y ? 0x3F80u : 0xBF80u;
            h.z = v.z ? 0x3F80u : 0xBF80u;
            h.w = v.w ? 0x3F80u : 0xBF80u;
            *reinterpret_cast<ushort4*>(&tile[row * 72 + seg + q * 4]) = h;
        }
    } else {
        // byte mode: 16 bytes = 1 uint4 per thread
        const unsigned char* w = (const unsigned char*)w_raw;
        uint4 v = *reinterpret_cast<const uint4*>(
            w + (size_t)(k0 + row) * N_TOT + n0 + seg);
        unsigned char b[16];
        *reinterpret_cast<uint4*>(b) = v;
        #pragma unroll
        for (int q = 0; q < 4; ++q) {
            ushort4 h;
            h.x = b[q * 4 + 0] ? 0x3F80u : 0xBF80u;
            h.y = b[q * 4 + 1] ? 0x3F80u : 0xBF80u;
            h.z = b[q * 4 + 2] ? 0x3F80u : 0xBF80u;
            h.w = b[q * 4 + 3] ? 0x3F80u : 0xBF80u;
            *reinterpret_cast<ushort4*>(&tile[row * 72 + seg + q * 4]) = h;
        }
    }
    __syncthreads();
    {   // write-out: thread -> (n, 16 consecutive k)
        int n = tid >> 2, kseg = (tid & 3) * 16;
        ushort4 o[4];
        #pragma unroll
        for (int j = 0; j < 16; ++j)
            ((unsigned short*)o)[j] = tile[(kseg + j) * 72 + n];
        ushort4* dst = reinterpret_cast<ushort4*>(wt + (size_t)(n0 + n) * K_TOT + k0 + kseg);
        dst[0] = o[0]; dst[1] = o[1]; dst[2] = o[2]; dst[3] = o[3];
    }
}

// ---------------- fused GEMM: out = scale * f2bf(X_f32) @ BT(bf16)^T ----------------
__global__ __launch_bounds__(256, 4) void fused_gemm(
    const float* __restrict__ X,             // [M][K] fp32
    const unsigned short* __restrict__ BT,   // [N][K] bf16 (pre-transposed W)
    const float* __restrict__ scale_p, float* __restrict__ out)
{
    // Unpadded LDS; bank balance via XOR chunk swizzle: LDS[r][c] holds global
    // chunk c^(r&7). For B (global_load_lds) the swizzle is on the SOURCE
    // address; for A (reg-staged) it is on the LDS ds_write address, so the
    // global fp32 reads stay linear (256 B contiguous per 8-lane group).
    __shared__ unsigned short As[128 * 64];  // 16 KiB
    __shared__ unsigned short Bs[128 * 64];

    const int tid  = threadIdx.x;
    const int lane = tid & 63;
    const int wave = tid >> 6;
    const int wm = (wave & 1) * 64;
    const int wn = (wave >> 1) * 64;

    // XCD-aware swizzle: all 8 blocks sharing an A m-strip get the same
    // (blockIdx % 8) -> same XCD under round-robin dispatch, within one
    // 64-block dispatch window -> one L2 fill per strip.
    const int j  = blockIdx.x & 7;
    const int s  = blockIdx.x >> 3;
    const int by = ((s >> 3) << 3) | j;   // 0..127
    const int bx = s & 7;                 // 0..7
    const int m0 = by * 128, n0 = bx * 128;

    const int fr = lane & 15, fq = lane >> 4;
    const float scale = scale_p[0];

    const int srow_l = lane >> 3;           // row within 8-row group
    const int gch    = lane & 7;            // global k-chunk (linear)
    const int lch    = gch ^ srow_l;        // LDS chunk for A scatter; r&7 == srow_l
    const int skch   = gch ^ srow_l;        // B source k-chunk (dest linear)

    f32x4 acc[4][4] = {};

    for (int k0 = 0; k0 < K_TOT; k0 += 64) {
        // B: async global->LDS, issued first so the DMA overlaps A conversion
        #pragma unroll
        for (int q = 0; q < 4; ++q) {
            const unsigned short* g = BT + (size_t)(n0 + wave * 32 + q * 8 + srow_l) * K_TOT
                                         + k0 + skch * 8;
            __builtin_amdgcn_global_load_lds(
                (const __attribute__((address_space(1))) void*)g,
                (__attribute__((address_space(3))) void*)&Bs[wave * 2048 + q * 512],
                16, 0, 0);
        }
        // A: fp32 -> bf16 reg-staging with XOR-chunk LDS scatter
        #pragma unroll
        for (int q = 0; q < 4; ++q) {
            const int r = wave * 32 + q * 8 + srow_l;
            const float4* g = reinterpret_cast<const float4*>(
                X + (size_t)(m0 + r) * K_TOT + k0 + gch * 8);
            float4 va = g[0];
            float4 vb = g[1];
            uint4 p;
            p.x = cvt_pk_bf16(va.x, va.y);
            p.y = cvt_pk_bf16(va.z, va.w);
            p.z = cvt_pk_bf16(vb.x, vb.y);
            p.w = cvt_pk_bf16(vb.z, vb.w);
            *reinterpret_cast<uint4*>(&As[r * 64 + lch * 8]) = p;  // ds_write_b128, conflict-free
        }
        __syncthreads();

        #pragma unroll
        for (int ks = 0; ks < 2; ++ks) {
            bf16x8 af[4], bfr[4];
            #pragma unroll
            for (int mi = 0; mi < 4; ++mi) {
                int r  = wm + mi * 16 + fr;
                int ch = (ks * 4 + fq) ^ (r & 7);
                af[mi] = *reinterpret_cast<const bf16x8*>(&As[r * 64 + ch * 8]);
            }
            #pragma unroll
            for (int ni = 0; ni < 4; ++ni) {
                int r  = wn + ni * 16 + fr;
                int ch = (ks * 4 + fq) ^ (r & 7);
                bfr[ni] = *reinterpret_cast<const bf16x8*>(&Bs[r * 64 + ch * 8]);
            }
            #pragma unroll
            for (int mi = 0; mi < 4; ++mi)
                #pragma unroll
                for (int ni = 0; ni < 4; ++ni)
                    acc[mi][ni] = __builtin_amdgcn_mfma_f32_16x16x32_bf16(
                        af[mi], bfr[ni], acc[mi][ni], 0, 0, 0);
        }
        __syncthreads();
    }

    // epilogue: C/D layout col = fr, row = fq*4 + j  (m89/m91-verified)
    #pragma unroll
    for (int mi = 0; mi < 4; ++mi) {
        #pragma unroll
        for (int ni = 0; ni < 4; ++ni) {
            const int col  = n0 + wn + ni * 16 + fr;
            const int rowb = m0 + wm + mi * 16 + fq * 4;
            #pragma unroll
            for (int jj = 0; jj < 4; ++jj)
                out[(size_t)(rowb + jj) * N_TOT + col] = scale * acc[mi][ni][jj];
        }
    }
}

// ---------------- fallback (ws too small): fused kernel, int32 weights ----------------
#define BKP 40
__global__ __launch_bounds__(256, 2) void binary_dense_gemm(
    const float* __restrict__ x, const int* __restrict__ kern,
    const float* __restrict__ scale_p, float* __restrict__ out)
{
    __shared__ unsigned short Asf[128 * BKP];
    __shared__ unsigned short Bsf[128 * BKP];
    const int tid = threadIdx.x, lane = tid & 63, wave = tid >> 6;
    const int wm = (wave & 1) * 64, wn = (wave >> 1) * 64;
    const int bx = blockIdx.x & 7, by = blockIdx.x >> 3;
    const int m0 = by * 128, n0 = bx * 128;
    const float scale = scale_p[0];
    const int fr = lane & 15, fq = lane >> 4;
    f32x4 acc[4][4] = {};
    for (int k0 = 0; k0 < K_TOT; k0 += 32) {
        #pragma unroll
        for (int i = 0; i < 4; ++i) {
            int slot = tid + i * 256, row = slot >> 3, kg = (slot & 7) << 2;
            const float4 v = *reinterpret_cast<const float4*>(x + (size_t)(m0 + row) * K_TOT + k0 + kg);
            ushort4 h;
            h.x = f2bf(v.x); h.y = f2bf(v.y); h.z = f2bf(v.z); h.w = f2bf(v.w);
            *reinterpret_cast<ushort4*>(&Asf[row * BKP + kg]) = h;
        }
        #pragma unroll
        for (int i = 0; i < 4; ++i) {
            int slot = tid + i * 256, nl = slot & 127, kg = (slot >> 7) << 2;
            ushort4 h;
            h.x = kern[(size_t)(k0 + kg + 0) * N_TOT + n0 + nl] ? 0x3F80u : 0xBF80u;
            h.y = kern[(size_t)(k0 + kg + 1) * N_TOT + n0 + nl] ? 0x3F80u : 0xBF80u;
            h.z = kern[(size_t)(k0 + kg + 2) * N_TOT + n0 + nl] ? 0x3F80u : 0xBF80u;
            h.w = kern[(size_t)(k0 + kg + 3) * N_TOT + n0 + nl] ? 0x3F80u : 0xBF80u;
            *reinterpret_cast<ushort4*>(&Bsf[nl * BKP + kg]) = h;
        }
        __syncthreads();
        bf16x8 af[4], bfr[4];
        #pragma unroll
        for (int mi = 0; mi < 4; ++mi)
            af[mi] = *reinterpret_cast<const bf16x8*>(&Asf[(wm + mi * 16 + fr) * BKP + fq * 8]);
        #pragma unroll
        for (int ni = 0; ni < 4; ++ni)
            bfr[ni] = *reinterpret_cast<const bf16x8*>(&Bsf[(wn + ni * 16 + fr) * BKP + fq * 8]);
        #pragma unroll
        for (int mi = 0; mi < 4; ++mi)
            #pragma unroll
            for (int ni = 0; ni < 4; ++ni)
                acc[mi][ni] = __builtin_amdgcn_mfma_f32_16x16x32_bf16(af[mi], bfr[ni], acc[mi][ni], 0, 0, 0);
        __syncthreads();
    }
    #pragma unroll
    for (int mi = 0; mi < 4; ++mi)
        #pragma unroll
        for (int ni = 0; ni < 4; ++ni) {
            const int col = n0 + wn + ni * 16 + fr;
            const int rowb = m0 + wm + mi * 16 + fq * 4;
            #pragma unroll
            for (int jj = 0; jj < 4; ++jj)
                out[(size_t)(rowb + jj) * N_TOT + col] = scale * acc[mi][ni][jj];
        }
}

extern "C" void kernel_launch(void* const* d_in, const int* in_sizes, int n_in,
                              void* d_out, int out_size, void* d_ws, size_t ws_size,
                              hipStream_t stream) {
    const float* x     = (const float*)d_in[0];
    const void*  kern  = d_in[1];
    const float* scale = (const float*)d_in[2];
    float*       out   = (float*)d_out;

    const size_t wt_bytes = (size_t)N_TOT * K_TOT * 2;   // 2 MiB
    const size_t flag_off = 256;                         // keep ws 16B-aligned
    if (ws_size >= flag_off + wt_bytes) {
        int*            flag = (int*)d_ws;
        unsigned short* wt   = (unsigned short*)((char*)d_ws + flag_off);
        // NOTE: in_sizes is in ELEMENTS, not bytes -> cannot distinguish byte
        // vs int32 bool storage host-side. Device-side detection (R5-proven).
        hipLaunchKernelGGL(detect_mode, dim3(1), dim3(256), 0, stream,
                           (const unsigned int*)kern, flag);
        hipLaunchKernelGGL(convert_w, dim3(256), dim3(256), 0, stream, kern, wt, flag);
        hipLaunchKernelGGL(fused_gemm, dim3(1024), dim3(256), 0, stream,
                           x, wt, scale, out);
    } else {
        hipLaunchKernelGGL(binary_dense_gemm, dim3(1024), dim3(256), 0, stream,
                           x, (const int*)kern, scale, out);
    }
}

// Round 3
// 166.629 us; speedup vs baseline: 1.1123x; 1.1123x over previous
//
#include <hip/hip_runtime.h>

// Binary-weight dense: out[M,N] = scale * x[M,K] @ W[K,N], W = kernel ? +1 : -1
// M = 16384, K = 1024, N = 1024.
// R8: fix R7's MLP collapse. R7's inline-asm v_cvt_pk_bf16_f32 in the A-staging
// loop made the compiler serialize per-q (load->wait->cvt->write, VGPR=56,
// VALUBusy 7.7%) -> 104 us. Per m240: never hand-write cvt_pk. Changes:
//  (1) scalar f2bf + phase-split staging: batch all 8 float4 loads into named
//      regs FIRST (A-loads issued before B DMA so cvt's vmcnt wait skips B),
//      then convert+ds_write.
//  (2) B double-buffered in LDS; A(t+1) reg-loads + B(t+1) DMA issued after
//      the frag ds_reads, before the MFMA cluster -> they fly under compute
//      and drain at the tail barrier (T14 split within __syncthreads).
//  (3) detect_mode merged into convert_w (each block scans first 4 KB as
//      uint32 - in-bounds in both encodings - and decides locally): 2 launches.

#define M_TOT 16384
#define N_TOT 1024
#define K_TOT 1024

typedef __attribute__((ext_vector_type(8))) short bf16x8;
typedef __attribute__((ext_vector_type(4))) float f32x4;

__device__ __forceinline__ unsigned short f2bf(float f) {
    unsigned int u = __builtin_bit_cast(unsigned int, f);
    u += 0x7FFFu + ((u >> 16) & 1u);   // round-to-nearest-even
    return (unsigned short)(u >> 16);
}

// ---------------- prepass: W bools [k][n] -> +-1 bf16 [n][k] ----------------
// Mode detection inlined: int32 bools -> first 1024 words all 0/1; byte bools
// -> some word >1 with overwhelming probability. First 4 KB is in-bounds in
// both encodings (byte buffer = 1 MiB). Deterministic -> all blocks agree.
__global__ __launch_bounds__(256) void convert_w(
    const void* __restrict__ w_raw, unsigned short* __restrict__ wt)
{
    __shared__ unsigned short tile[64 * 72];
    __shared__ int smode;
    const int tid = threadIdx.x;
    const int k0 = (blockIdx.x & 15) * 64;
    const int n0 = (blockIdx.x >> 4) * 64;
    const int row = tid >> 2;            // k-local
    const int seg = (tid & 3) * 16;      // n-local group of 16

    if (tid == 0) smode = 0;
    __syncthreads();
    {
        const unsigned int* k32 = (const unsigned int*)w_raw;
        int bad = 0;
        for (int i = tid; i < 1024; i += 256)
            bad |= (k32[i] > 1u) ? 1 : 0;
        if (bad) atomicOr(&smode, 1);
    }
    __syncthreads();

    if (smode == 0) {
        // int32 mode: 16 ints = 4 uint4 per thread
        const unsigned int* w = (const unsigned int*)w_raw;
        const uint4* src = reinterpret_cast<const uint4*>(
            w + (size_t)(k0 + row) * N_TOT + n0 + seg);
        #pragma unroll
        for (int q = 0; q < 4; ++q) {
            uint4 v = src[q];
            ushort4 h;
            h.x = v.x ? 0x3F80u : 0xBF80u;
            h.y = v.y ? 0x3F80u : 0xBF80u;
            h.z = v.z ? 0x3F80u : 0xBF80u;
            h.w = v.w ? 0x3F80u : 0xBF80u;
            *reinterpret_cast<ushort4*>(&tile[row * 72 + seg + q * 4]) = h;
        }
    } else {
        // byte mode: 16 bytes = 1 uint4 per thread
        const unsigned char* w = (const unsigned char*)w_raw;
        uint4 v = *reinterpret_cast<const uint4*>(
            w + (size_t)(k0 + row) * N_TOT + n0 + seg);
        unsigned char b[16];
        *reinterpret_cast<uint4*>(b) = v;
        #pragma unroll
        for (int q = 0; q < 4; ++q) {
            ushort4 h;
            h.x = b[q * 4 + 0] ? 0x3F80u : 0xBF80u;
            h.y = b[q * 4 + 1] ? 0x3F80u : 0xBF80u;
            h.z = b[q * 4 + 2] ? 0x3F80u : 0xBF80u;
            h.w = b[q * 4 + 3] ? 0x3F80u : 0xBF80u;
            *reinterpret_cast<ushort4*>(&tile[row * 72 + seg + q * 4]) = h;
        }
    }
    __syncthreads();
    {   // write-out: thread -> (n, 16 consecutive k)
        int n = tid >> 2, kseg = (tid & 3) * 16;
        ushort4 o[4];
        #pragma unroll
        for (int j = 0; j < 16; ++j)
            ((unsigned short*)o)[j] = tile[(kseg + j) * 72 + n];
        ushort4* dst = reinterpret_cast<ushort4*>(wt + (size_t)(n0 + n) * K_TOT + k0 + kseg);
        dst[0] = o[0]; dst[1] = o[1]; dst[2] = o[2]; dst[3] = o[3];
    }
}

// ---------------- fused GEMM: out = scale * f2bf(X_f32) @ BT(bf16)^T ----------------
__global__ __launch_bounds__(256) void fused_gemm(
    const float* __restrict__ X,             // [M][K] fp32
    const unsigned short* __restrict__ BT,   // [N][K] bf16 (pre-transposed W)
    const float* __restrict__ scale_p, float* __restrict__ out)
{
    // As single-buffered (written from regs at iter top, reads complete at the
    // prior tail barrier). Bs double-buffered (DMA(t+1) lands while Bs[cur] is
    // read). XOR chunk swizzle: LDS[r][c] holds global chunk c^(r&7); applied
    // on the ds_write address for A (linear global reads) and on the SOURCE
    // address for B (global_load_lds dest must stay linear, m104).
    __shared__ unsigned short As[128 * 64];        // 16 KiB
    __shared__ unsigned short Bs[2][128 * 64];     // 32 KiB

    const int tid  = threadIdx.x;
    const int lane = tid & 63;
    const int wave = tid >> 6;
    const int wm = (wave & 1) * 64;
    const int wn = (wave >> 1) * 64;

    // XCD-aware swizzle: all 8 blocks sharing an A m-strip keep the same
    // (blockIdx % 8) -> same XCD under round-robin dispatch, within one
    // 64-block window -> one L2 fill per strip.
    const int j  = blockIdx.x & 7;
    const int s  = blockIdx.x >> 3;
    const int by = ((s >> 3) << 3) | j;   // 0..127
    const int bx = s & 7;                 // 0..7
    const int m0 = by * 128, n0 = bx * 128;

    const int fr = lane & 15, fq = lane >> 4;
    const float scale = scale_p[0];

    const int srow_l = lane >> 3;           // row within 8-row group
    const int gch    = lane & 7;            // global k-chunk (linear)
    const int lch    = gch ^ srow_l;        // LDS chunk for A scatter; r&7 == srow_l
    const int skch   = gch ^ srow_l;        // B source k-chunk (dest linear)
    const int arow   = wave * 32 + srow_l;  // staging row base (+ q*8)

    f32x4 acc[4][4] = {};
    float4 va[4], vb[4];

    // ---- prologue: A(0) -> regs, B(0) -> Bs[0] via DMA ----
    #pragma unroll
    for (int q = 0; q < 4; ++q) {
        const float4* g = reinterpret_cast<const float4*>(
            X + (size_t)(m0 + arow + q * 8) * K_TOT + gch * 8);
        va[q] = g[0];
        vb[q] = g[1];
    }
    #pragma unroll
    for (int q = 0; q < 4; ++q) {
        const unsigned short* g = BT + (size_t)(n0 + arow + q * 8) * K_TOT + skch * 8;
        __builtin_amdgcn_global_load_lds(
            (const __attribute__((address_space(1))) void*)g,
            (__attribute__((address_space(3))) void*)&Bs[0][wave * 2048 + q * 512],
            16, 0, 0);
    }

    for (int t = 0; t < 16; ++t) {
        const int cur = t & 1;

        // A(t): convert regs -> LDS (scalar f2bf; compiler schedules/packs)
        #pragma unroll
        for (int q = 0; q < 4; ++q) {
            uint4 p;
            p.x = (unsigned)f2bf(va[q].x) | ((unsigned)f2bf(va[q].y) << 16);
            p.y = (unsigned)f2bf(va[q].z) | ((unsigned)f2bf(va[q].w) << 16);
            p.z = (unsigned)f2bf(vb[q].x) | ((unsigned)f2bf(vb[q].y) << 16);
            p.w = (unsigned)f2bf(vb[q].z) | ((unsigned)f2bf(vb[q].w) << 16);
            *reinterpret_cast<uint4*>(&As[(arow + q * 8) * 64 + lch * 8]) = p;
        }
        __syncthreads();   // drains B-DMA(t) + As writes

        // all fragment reads for both ks halves (16 x ds_read_b128)
        bf16x8 af[2][4], bfr[2][4];
        #pragma unroll
        for (int ks = 0; ks < 2; ++ks) {
            #pragma unroll
            for (int mi = 0; mi < 4; ++mi) {
                int r  = wm + mi * 16 + fr;
                int ch = (ks * 4 + fq) ^ (r & 7);
                af[ks][mi] = *reinterpret_cast<const bf16x8*>(&As[r * 64 + ch * 8]);
            }
            #pragma unroll
            for (int ni = 0; ni < 4; ++ni) {
                int r  = wn + ni * 16 + fr;
                int ch = (ks * 4 + fq) ^ (r & 7);
                bfr[ks][ni] = *reinterpret_cast<const bf16x8*>(&Bs[cur][r * 64 + ch * 8]);
            }
        }

        // prefetch t+1: A -> regs, B -> Bs[cur^1]; flies under the MFMA cluster,
        // drains at the tail barrier (had the whole compute phase in flight).
        if (t < 15) {
            const int kn = (t + 1) * 64;
            #pragma unroll
            for (int q = 0; q < 4; ++q) {
                const float4* g = reinterpret_cast<const float4*>(
                    X + (size_t)(m0 + arow + q * 8) * K_TOT + kn + gch * 8);
                va[q] = g[0];
                vb[q] = g[1];
            }
            #pragma unroll
            for (int q = 0; q < 4; ++q) {
                const unsigned short* g = BT + (size_t)(n0 + arow + q * 8) * K_TOT + kn + skch * 8;
                __builtin_amdgcn_global_load_lds(
                    (const __attribute__((address_space(1))) void*)g,
                    (__attribute__((address_space(3))) void*)&Bs[cur ^ 1][wave * 2048 + q * 512],
                    16, 0, 0);
            }
        }

        #pragma unroll
        for (int ks = 0; ks < 2; ++ks)
            #pragma unroll
            for (int mi = 0; mi < 4; ++mi)
                #pragma unroll
                for (int ni = 0; ni < 4; ++ni)
                    acc[mi][ni] = __builtin_amdgcn_mfma_f32_16x16x32_bf16(
                        af[ks][mi], bfr[ks][ni], acc[mi][ni], 0, 0, 0);

        __syncthreads();   // reads(t) done; prefetch(t+1) drained here
    }

    // epilogue: C/D layout col = fr, row = fq*4 + j  (m89/m91-verified)
    #pragma unroll
    for (int mi = 0; mi < 4; ++mi) {
        #pragma unroll
        for (int ni = 0; ni < 4; ++ni) {
            const int col  = n0 + wn + ni * 16 + fr;
            const int rowb = m0 + wm + mi * 16 + fq * 4;
            #pragma unroll
            for (int jj = 0; jj < 4; ++jj)
                out[(size_t)(rowb + jj) * N_TOT + col] = scale * acc[mi][ni][jj];
        }
    }
}

// ---------------- fallback (ws too small): fused kernel, int32 weights ----------------
#define BKP 40
__global__ __launch_bounds__(256, 2) void binary_dense_gemm(
    const float* __restrict__ x, const int* __restrict__ kern,
    const float* __restrict__ scale_p, float* __restrict__ out)
{
    __shared__ unsigned short Asf[128 * BKP];
    __shared__ unsigned short Bsf[128 * BKP];
    const int tid = threadIdx.x, lane = tid & 63, wave = tid >> 6;
    const int wm = (wave & 1) * 64, wn = (wave >> 1) * 64;
    const int bx = blockIdx.x & 7, by = blockIdx.x >> 3;
    const int m0 = by * 128, n0 = bx * 128;
    const float scale = scale_p[0];
    const int fr = lane & 15, fq = lane >> 4;
    f32x4 acc[4][4] = {};
    for (int k0 = 0; k0 < K_TOT; k0 += 32) {
        #pragma unroll
        for (int i = 0; i < 4; ++i) {
            int slot = tid + i * 256, row = slot >> 3, kg = (slot & 7) << 2;
            const float4 v = *reinterpret_cast<const float4*>(x + (size_t)(m0 + row) * K_TOT + k0 + kg);
            ushort4 h;
            h.x = f2bf(v.x); h.y = f2bf(v.y); h.z = f2bf(v.z); h.w = f2bf(v.w);
            *reinterpret_cast<ushort4*>(&Asf[row * BKP + kg]) = h;
        }
        #pragma unroll
        for (int i = 0; i < 4; ++i) {
            int slot = tid + i * 256, nl = slot & 127, kg = (slot >> 7) << 2;
            ushort4 h;
            h.x = kern[(size_t)(k0 + kg + 0) * N_TOT + n0 + nl] ? 0x3F80u : 0xBF80u;
            h.y = kern[(size_t)(k0 + kg + 1) * N_TOT + n0 + nl] ? 0x3F80u : 0xBF80u;
            h.z = kern[(size_t)(k0 + kg + 2) * N_TOT + n0 + nl] ? 0x3F80u : 0xBF80u;
            h.w = kern[(size_t)(k0 + kg + 3) * N_TOT + n0 + nl] ? 0x3F80u : 0xBF80u;
            *reinterpret_cast<ushort4*>(&Bsf[nl * BKP + kg]) = h;
        }
        __syncthreads();
        bf16x8 af[4], bfr[4];
        #pragma unroll
        for (int mi = 0; mi < 4; ++mi)
            af[mi] = *reinterpret_cast<const bf16x8*>(&Asf[(wm + mi * 16 + fr) * BKP + fq * 8]);
        #pragma unroll
        for (int ni = 0; ni < 4; ++ni)
            bfr[ni] = *reinterpret_cast<const bf16x8*>(&Bsf[(wn + ni * 16 + fr) * BKP + fq * 8]);
        #pragma unroll
        for (int mi = 0; mi < 4; ++mi)
            #pragma unroll
            for (int ni = 0; ni < 4; ++ni)
                acc[mi][ni] = __builtin_amdgcn_mfma_f32_16x16x32_bf16(af[mi], bfr[ni], acc[mi][ni], 0, 0, 0);
        __syncthreads();
    }
    #pragma unroll
    for (int mi = 0; mi < 4; ++mi)
        #pragma unroll
        for (int ni = 0; ni < 4; ++ni) {
            const int col = n0 + wn + ni * 16 + fr;
            const int rowb = m0 + wm + mi * 16 + fq * 4;
            #pragma unroll
            for (int jj = 0; jj < 4; ++jj)
                out[(size_t)(rowb + jj) * N_TOT + col] = scale * acc[mi][ni][jj];
        }
}

extern "C" void kernel_launch(void* const* d_in, const int* in_sizes, int n_in,
                              void* d_out, int out_size, void* d_ws, size_t ws_size,
                              hipStream_t stream) {
    const float* x     = (const float*)d_in[0];
    const void*  kern  = d_in[1];
    const float* scale = (const float*)d_in[2];
    float*       out   = (float*)d_out;

    const size_t wt_bytes = (size_t)N_TOT * K_TOT * 2;   // 2 MiB
    const size_t wt_off   = 256;                         // keep ws 16B-aligned
    if (ws_size >= wt_off + wt_bytes) {
        unsigned short* wt = (unsigned short*)((char*)d_ws + wt_off);
        hipLaunchKernelGGL(convert_w, dim3(256), dim3(256), 0, stream, kern, wt);
        hipLaunchKernelGGL(fused_gemm, dim3(1024), dim3(256), 0, stream,
                           x, wt, scale, out);
    } else {
        hipLaunchKernelGGL(binary_dense_gemm, dim3(1024), dim3(256), 0, stream,
                           x, (const int*)kern, scale, out);
    }
}

// Round 4
// 154.674 us; speedup vs baseline: 1.1982x; 1.0773x over previous
//
#include <hip/hip_runtime.h>

// Binary-weight dense: out[M,N] = scale * x[M,K] @ W[K,N], W = kernel ? +1 : -1
// M = 16384, K = 1024, N = 1024.
// R9: revert to the proven-fast GEMM, consolidate the prepass.
// Accounting across R5/R7/R8 fits total = base(~55us) + ~6.6us/launch + kernels.
// R5's bf16_gemm moved 100 MB (34.6 FETCH = exactly unique inputs + 65.5 WRITE)
// in 51.9us = 2.0 TB/s; the fused A-fp32 GEMM (R8) moved 119 MB at 1.26 TB/s in
// ~92us -> fusion was a net loss (prefetch drains at the tail __syncthreads'
// vmcnt(0) every iter; 3 blocks/CU vs 4). So:
//  (1) GEMM = byte-for-byte R5 bf16_gemm (51.4-51.9us measured).
//  (2) ONE prep kernel: blocks [0,256) = convert_w with inlined mode detect
//      (scan first 4KB as uint32, in-bounds in both encodings, deterministic);
//      blocks [256,4352) = convert_x fp32->bf16. Saves 2 launches (~13us) and
//      overlaps W with X conversion.

#define M_TOT 16384
#define N_TOT 1024
#define K_TOT 1024

typedef __attribute__((ext_vector_type(8))) short bf16x8;
typedef __attribute__((ext_vector_type(4))) float f32x4;

__device__ __forceinline__ unsigned short f2bf(float f) {
    unsigned int u = __builtin_bit_cast(unsigned int, f);
    u += 0x7FFFu + ((u >> 16) & 1u);   // round-to-nearest-even
    return (unsigned short)(u >> 16);
}

// ---------------- prep: convert_w (blocks 0..255) + convert_x (blocks 256+) ----------------
// X part: 4096 blocks x 256 threads x 4 float4 = 64 MB fp32 -> 32 MB bf16.
// W part: bools [k][n] -> +-1 bf16 [n][k]; mode detect inlined (int32 bools ->
// first 1024 words all 0/1; byte bools -> some word >1 w.p. ~1).
__global__ __launch_bounds__(256) void prep(
    const void* __restrict__ w_raw, unsigned short* __restrict__ wt,
    const float4* __restrict__ x, ushort4* __restrict__ xb)
{
    __shared__ unsigned short tile[64 * 72];
    __shared__ int smode;
    const int tid = threadIdx.x;

    if (blockIdx.x >= 256) {
        // ---- convert_x ----
        const int S = 4096 * 256;
        int g = (blockIdx.x - 256) * 256 + tid;
        #pragma unroll
        for (int j = 0; j < 4; ++j) {
            int idx = g + j * S;
            float4 v = x[idx];
            ushort4 h;
            h.x = f2bf(v.x); h.y = f2bf(v.y); h.z = f2bf(v.z); h.w = f2bf(v.w);
            xb[idx] = h;
        }
        return;
    }

    // ---- convert_w ----
    const int k0 = (blockIdx.x & 15) * 64;
    const int n0 = (blockIdx.x >> 4) * 64;
    const int row = tid >> 2;            // k-local
    const int seg = (tid & 3) * 16;      // n-local group of 16

    if (tid == 0) smode = 0;
    __syncthreads();
    {
        const unsigned int* k32 = (const unsigned int*)w_raw;
        int bad = 0;
        for (int i = tid; i < 1024; i += 256)
            bad |= (k32[i] > 1u) ? 1 : 0;
        if (bad) atomicOr(&smode, 1);
    }
    __syncthreads();

    if (smode == 0) {
        // int32 mode: 16 ints = 4 uint4 per thread
        const unsigned int* w = (const unsigned int*)w_raw;
        const uint4* src = reinterpret_cast<const uint4*>(
            w + (size_t)(k0 + row) * N_TOT + n0 + seg);
        #pragma unroll
        for (int q = 0; q < 4; ++q) {
            uint4 v = src[q];
            ushort4 h;
            h.x = v.x ? 0x3F80u : 0xBF80u;
            h.y = v.y ? 0x3F80u : 0xBF80u;
            h.z = v.z ? 0x3F80u : 0xBF80u;
            h.w = v.w ? 0x3F80u : 0xBF80u;
            *reinterpret_cast<ushort4*>(&tile[row * 72 + seg + q * 4]) = h;
        }
    } else {
        // byte mode: 16 bytes = 1 uint4 per thread
        const unsigned char* w = (const unsigned char*)w_raw;
        uint4 v = *reinterpret_cast<const uint4*>(
            w + (size_t)(k0 + row) * N_TOT + n0 + seg);
        unsigned char b[16];
        *reinterpret_cast<uint4*>(b) = v;
        #pragma unroll
        for (int q = 0; q < 4; ++q) {
            ushort4 h;
            h.x = b[q * 4 + 0] ? 0x3F80u : 0xBF80u;
            h.y = b[q * 4 + 1] ? 0x3F80u : 0xBF80u;
            h.z = b[q * 4 + 2] ? 0x3F80u : 0xBF80u;
            h.w = b[q * 4 + 3] ? 0x3F80u : 0xBF80u;
            *reinterpret_cast<ushort4*>(&tile[row * 72 + seg + q * 4]) = h;
        }
    }
    __syncthreads();
    {   // write-out: thread -> (n, 16 consecutive k)
        int n = tid >> 2, kseg = (tid & 3) * 16;
        ushort4 o[4];
        #pragma unroll
        for (int j = 0; j < 16; ++j)
            ((unsigned short*)o)[j] = tile[(kseg + j) * 72 + n];
        ushort4* dst = reinterpret_cast<ushort4*>(wt + (size_t)(n0 + n) * K_TOT + k0 + kseg);
        dst[0] = o[0]; dst[1] = o[1]; dst[2] = o[2]; dst[3] = o[3];
    }
}

// ---------------- main GEMM: out = scale * A(bf16) @ BT(bf16)^T ----------------
// Byte-for-byte the R5 kernel (51.4-51.9 us measured): 128x128x64 tile,
// global_load_lds w=16 for both operands, XOR chunk swizzle (LDS[r][c] holds
// global chunk c^(r&7), applied on the SOURCE address), 16x16x32 bf16 MFMA,
// XCD-aware block swizzle (8 same-strip blocks share blockIdx%8 -> one XCD).
__global__ __launch_bounds__(256) void bf16_gemm(
    const unsigned short* __restrict__ A,    // [M][K] bf16
    const unsigned short* __restrict__ BT,   // [N][K] bf16 (pre-transposed W)
    const float* __restrict__ scale_p, float* __restrict__ out)
{
    __shared__ unsigned short As[128 * 64];  // 16 KiB
    __shared__ unsigned short Bs[128 * 64];

    const int tid  = threadIdx.x;
    const int lane = tid & 63;
    const int wave = tid >> 6;
    const int wm = (wave & 1) * 64;
    const int wn = (wave >> 1) * 64;

    const int j  = blockIdx.x & 7;
    const int s  = blockIdx.x >> 3;
    const int by = ((s >> 3) << 3) | j;   // 0..127
    const int bx = s & 7;                 // 0..7
    const int m0 = by * 128, n0 = bx * 128;

    const int fr = lane & 15, fq = lane >> 4;
    const float scale = scale_p[0];

    // staging: issue q of wave w covers LDS rows w*32+q*8 .. +8; lane i lands at
    // row w*32+q*8+(i>>3), LDS chunk i&7; source global k-chunk = (i&7)^(i>>3).
    const int srow = wave * 32 + (lane >> 3);
    const int skch = (lane & 7) ^ (lane >> 3);

    f32x4 acc[4][4] = {};

    for (int k0 = 0; k0 < K_TOT; k0 += 64) {
        #pragma unroll
        for (int q = 0; q < 4; ++q) {
            const unsigned short* g = A + (size_t)(m0 + srow + q * 8) * K_TOT + k0 + skch * 8;
            __builtin_amdgcn_global_load_lds(
                (const __attribute__((address_space(1))) void*)g,
                (__attribute__((address_space(3))) void*)&As[wave * 2048 + q * 512],
                16, 0, 0);
        }
        #pragma unroll
        for (int q = 0; q < 4; ++q) {
            const unsigned short* g = BT + (size_t)(n0 + srow + q * 8) * K_TOT + k0 + skch * 8;
            __builtin_amdgcn_global_load_lds(
                (const __attribute__((address_space(1))) void*)g,
                (__attribute__((address_space(3))) void*)&Bs[wave * 2048 + q * 512],
                16, 0, 0);
        }
        __syncthreads();

        #pragma unroll
        for (int ks = 0; ks < 2; ++ks) {
            bf16x8 af[4], bfr[4];
            #pragma unroll
            for (int mi = 0; mi < 4; ++mi) {
                int r  = wm + mi * 16 + fr;
                int ch = (ks * 4 + fq) ^ (r & 7);
                af[mi] = *reinterpret_cast<const bf16x8*>(&As[r * 64 + ch * 8]);
            }
            #pragma unroll
            for (int ni = 0; ni < 4; ++ni) {
                int r  = wn + ni * 16 + fr;
                int ch = (ks * 4 + fq) ^ (r & 7);
                bfr[ni] = *reinterpret_cast<const bf16x8*>(&Bs[r * 64 + ch * 8]);
            }
            #pragma unroll
            for (int mi = 0; mi < 4; ++mi)
                #pragma unroll
                for (int ni = 0; ni < 4; ++ni)
                    acc[mi][ni] = __builtin_amdgcn_mfma_f32_16x16x32_bf16(
                        af[mi], bfr[ni], acc[mi][ni], 0, 0, 0);
        }
        __syncthreads();
    }

    // epilogue: C/D layout col = fr, row = fq*4 + j  (m89/m91-verified)
    #pragma unroll
    for (int mi = 0; mi < 4; ++mi) {
        #pragma unroll
        for (int ni = 0; ni < 4; ++ni) {
            const int col  = n0 + wn + ni * 16 + fr;
            const int rowb = m0 + wm + mi * 16 + fq * 4;
            #pragma unroll
            for (int jj = 0; jj < 4; ++jj)
                out[(size_t)(rowb + jj) * N_TOT + col] = scale * acc[mi][ni][jj];
        }
    }
}

// ---------------- fallback (ws too small): fused kernel, int32 weights ----------------
#define BKP 40
__global__ __launch_bounds__(256, 2) void binary_dense_gemm(
    const float* __restrict__ x, const int* __restrict__ kern,
    const float* __restrict__ scale_p, float* __restrict__ out)
{
    __shared__ unsigned short Asf[128 * BKP];
    __shared__ unsigned short Bsf[128 * BKP];
    const int tid = threadIdx.x, lane = tid & 63, wave = tid >> 6;
    const int wm = (wave & 1) * 64, wn = (wave >> 1) * 64;
    const int bx = blockIdx.x & 7, by = blockIdx.x >> 3;
    const int m0 = by * 128, n0 = bx * 128;
    const float scale = scale_p[0];
    const int fr = lane & 15, fq = lane >> 4;
    f32x4 acc[4][4] = {};
    for (int k0 = 0; k0 < K_TOT; k0 += 32) {
        #pragma unroll
        for (int i = 0; i < 4; ++i) {
            int slot = tid + i * 256, row = slot >> 3, kg = (slot & 7) << 2;
            const float4 v = *reinterpret_cast<const float4*>(x + (size_t)(m0 + row) * K_TOT + k0 + kg);
            ushort4 h;
            h.x = f2bf(v.x); h.y = f2bf(v.y); h.z = f2bf(v.z); h.w = f2bf(v.w);
            *reinterpret_cast<ushort4*>(&Asf[row * BKP + kg]) = h;
        }
        #pragma unroll
        for (int i = 0; i < 4; ++i) {
            int slot = tid + i * 256, nl = slot & 127, kg = (slot >> 7) << 2;
            ushort4 h;
            h.x = kern[(size_t)(k0 + kg + 0) * N_TOT + n0 + nl] ? 0x3F80u : 0xBF80u;
            h.y = kern[(size_t)(k0 + kg + 1) * N_TOT + n0 + nl] ? 0x3F80u : 0xBF80u;
            h.z = kern[(size_t)(k0 + kg + 2) * N_TOT + n0 + nl] ? 0x3F80u : 0xBF80u;
            h.w = kern[(size_t)(k0 + kg + 3) * N_TOT + n0 + nl] ? 0x3F80u : 0xBF80u;
            *reinterpret_cast<ushort4*>(&Bsf[nl * BKP + kg]) = h;
        }
        __syncthreads();
        bf16x8 af[4], bfr[4];
        #pragma unroll
        for (int mi = 0; mi < 4; ++mi)
            af[mi] = *reinterpret_cast<const bf16x8*>(&Asf[(wm + mi * 16 + fr) * BKP + fq * 8]);
        #pragma unroll
        for (int ni = 0; ni < 4; ++ni)
            bfr[ni] = *reinterpret_cast<const bf16x8*>(&Bsf[(wn + ni * 16 + fr) * BKP + fq * 8]);
        #pragma unroll
        for (int mi = 0; mi < 4; ++mi)
            #pragma unroll
            for (int ni = 0; ni < 4; ++ni)
                acc[mi][ni] = __builtin_amdgcn_mfma_f32_16x16x32_bf16(af[mi], bfr[ni], acc[mi][ni], 0, 0, 0);
        __syncthreads();
    }
    #pragma unroll
    for (int mi = 0; mi < 4; ++mi)
        #pragma unroll
        for (int ni = 0; ni < 4; ++ni) {
            const int col = n0 + wn + ni * 16 + fr;
            const int rowb = m0 + wm + mi * 16 + fq * 4;
            #pragma unroll
            for (int jj = 0; jj < 4; ++jj)
                out[(size_t)(rowb + jj) * N_TOT + col] = scale * acc[mi][ni][jj];
        }
}

extern "C" void kernel_launch(void* const* d_in, const int* in_sizes, int n_in,
                              void* d_out, int out_size, void* d_ws, size_t ws_size,
                              hipStream_t stream) {
    const float* x     = (const float*)d_in[0];
    const void*  kern  = d_in[1];
    const float* scale = (const float*)d_in[2];
    float*       out   = (float*)d_out;

    const size_t xb_bytes = (size_t)M_TOT * K_TOT * 2;           // 32 MiB
    const size_t wt_bytes = (size_t)N_TOT * K_TOT * 2;           //  2 MiB
    const size_t xb_off   = 256;                                 // 16B-aligned
    if (ws_size >= xb_off + xb_bytes + wt_bytes) {
        unsigned short* xb = (unsigned short*)((char*)d_ws + xb_off);
        unsigned short* wt = (unsigned short*)((char*)d_ws + xb_off + xb_bytes);
        hipLaunchKernelGGL(prep, dim3(256 + 4096), dim3(256), 0, stream,
                           kern, wt, (const float4*)x, (ushort4*)xb);
        hipLaunchKernelGGL(bf16_gemm, dim3(1024), dim3(256), 0, stream,
                           xb, wt, scale, out);
    } else {
        hipLaunchKernelGGL(binary_dense_gemm, dim3(1024), dim3(256), 0, stream,
                           x, (const int*)kern, scale, out);
    }
}